// Round 5
// baseline (209.304 us; speedup 1.0000x reference)
//
#include <hip/hip_runtime.h>
#include <hip/hip_bf16.h>

typedef __attribute__((ext_vector_type(8))) unsigned short us8;
typedef __attribute__((ext_vector_type(4))) unsigned short us4;
typedef __attribute__((ext_vector_type(8))) short short8;
typedef __attribute__((ext_vector_type(4))) float f32x4;

#define BB 2048
#define NN 64
#define CIN 128
#define CO 256
#define KWIN 3
#define EE 256
#define NE 320            // E + N (self loops)
#define EPSBN 1e-5f

static __device__ __forceinline__ void gload_lds16(const unsigned short* g, unsigned short* l) {
    __builtin_amdgcn_global_load_lds(
        (const __attribute__((address_space(1))) unsigned int*)g,
        (__attribute__((address_space(3))) unsigned int*)l,
        16, 0, 0);
}

static __device__ __forceinline__ float bf2f(unsigned short u) {
    return __uint_as_float(((unsigned int)u) << 16);
}

static __device__ __forceinline__ unsigned short f2bfu(float f) {
    unsigned int u = __float_as_uint(f);
    u = (u + 0x7FFFu + ((u >> 16) & 1u)) >> 16;   // RN-even
    return (unsigned short)u;
}

// ---------------- kernel 1: dense normalized adjacency Ahat[dst][src] (bf16), deterministic ----------------
__global__ __launch_bounds__(320) void k_setup(const int* __restrict__ ei,
                                               __hip_bfloat16* __restrict__ Ahat) {
    __shared__ int s_cnt[NN * NN];   // 16 KB
    __shared__ int s_deg[NN];
    __shared__ float s_dinv[NN];
    const int t = threadIdx.x;
    for (int i = t; i < NN * NN; i += 320) s_cnt[i] = 0;
    if (t < NN) s_deg[t] = 0;
    __syncthreads();
    int src, dst;
    if (t < EE) { src = ei[t]; dst = ei[EE + t]; }
    else        { src = t - EE; dst = t - EE; }
    atomicAdd(&s_deg[dst], 1);                 // integer: order-independent, deterministic
    atomicAdd(&s_cnt[dst * NN + src], 1);
    __syncthreads();
    if (t < NN) s_dinv[t] = rsqrtf((float)s_deg[t]);   // deg >= 1 (self loop)
    __syncthreads();
    for (int i = t; i < NN * NN; i += 320) {
        const int n = i >> 6, m = i & 63;
        Ahat[i] = __float2bfloat16((float)s_cnt[i] * s_dinv[m] * s_dinv[n]);
    }
}

// ---------------- kernel 2: pack weights: Wt[o][c]=W[c][o]; W2t[o][kk*256+i]=wconv[o][i][kk] ----------------
__global__ __launch_bounds__(256) void k_weights(const float* __restrict__ W,
                                                 const float* __restrict__ wconv,
                                                 __hip_bfloat16* __restrict__ Wt,
                                                 __hip_bfloat16* __restrict__ W2t) {
    const int idx = blockIdx.x * 256 + threadIdx.x;
    if (idx < CO * CIN) {                                 // 32768
        const int o = idx >> 7, c = idx & 127;
        Wt[idx] = __float2bfloat16(W[c * CO + o]);
    }
    const int j = idx - CO * CIN;
    if (j >= 0 && j < CO * KWIN * CO) {                   // 196608
        const int o = j / 768, q = j - o * 768;
        const int kk = q >> 8, i = q & 255;
        W2t[j] = __float2bfloat16(wconv[(o * CO + i) * KWIN + kk]);
    }
}

// ---------------- kernel 3: fused GCN via MFMA: xgcn = Ahat @ (x[b] @ W) + bgcn ----------------
// Output layout: xgcn[n][b][o]  (node-major, so conv A-stage is contiguous in b)
__global__ __launch_bounds__(256) void k_gcn(const float* __restrict__ x,
                                             const __hip_bfloat16* __restrict__ Ahat_,
                                             const __hip_bfloat16* __restrict__ Wt_,
                                             const float* __restrict__ bgcn,
                                             __hip_bfloat16* __restrict__ xgcn_) {
    __shared__ __align__(16) unsigned short sx[64 * 128];    // [m][c] swizzled, 16 KB
    __shared__ __align__(16) unsigned short stm[256 * 64];   // [o][m] swizzled, 32 KB (wave-private rows)
    const unsigned short* Ahat = (const unsigned short*)Ahat_;
    const unsigned short* Wt   = (const unsigned short*)Wt_;
    unsigned short* xgcn = (unsigned short*)xgcn_;

    const int b = blockIdx.x, tid = threadIdx.x;
    const int lane = tid & 63, wid = tid >> 6;
    const int llo = lane & 15, lhi = lane >> 4;

    // ---- stage x[b] f32 -> sx bf16 [m][c], XOR-swizzled cols, row-contiguous writes ----
#pragma unroll
    for (int r = 0; r < 4; ++r) {
        const int f = tid + 256 * r;
        const int m = f >> 4, c0 = (f & 15) * 8;
        const float4* src = (const float4*)(x + ((size_t)b * NN + m) * CIN + c0);
        const float4 v0 = src[0], v1 = src[1];
        unsigned short t8[8] = {f2bfu(v0.x), f2bfu(v0.y), f2bfu(v0.z), f2bfu(v0.w),
                                f2bfu(v1.x), f2bfu(v1.y), f2bfu(v1.z), f2bfu(v1.w)};
        *(us8*)&sx[m * 128 + (c0 ^ ((m & 7) << 3))] = *(const us8*)t8;
    }
    __syncthreads();

    // ---- G1: tmp2 = x[b] @ W; wave owns o-cols wid*64..+64 ----
    f32x4 acc1[4][4];
#pragma unroll
    for (int p = 0; p < 4; ++p)
#pragma unroll
        for (int q = 0; q < 4; ++q) acc1[p][q] = (f32x4){0.f, 0.f, 0.f, 0.f};
#pragma unroll
    for (int s = 0; s < 4; ++s) {
        const int k0 = s * 32 + lhi * 8;
        short8 af[4], bf[4];
#pragma unroll
        for (int p = 0; p < 4; ++p) {
            const int m = p * 16 + llo;
            af[p] = *(const short8*)&sx[m * 128 + (k0 ^ ((m & 7) << 3))];
        }
#pragma unroll
        for (int q = 0; q < 4; ++q) {
            const int o = wid * 64 + q * 16 + llo;
            bf[q] = *(const short8*)&Wt[o * 128 + k0];   // global, L2-hot
        }
#pragma unroll
        for (int p = 0; p < 4; ++p)
#pragma unroll
            for (int q = 0; q < 4; ++q)
                acc1[p][q] = __builtin_amdgcn_mfma_f32_16x16x32_bf16(af[p], bf[q], acc1[p][q], 0, 0, 0);
    }
    // tmp2 -> stm [o][m] swizzled; wave-private rows -> no barrier needed
#pragma unroll
    for (int p = 0; p < 4; ++p)
#pragma unroll
        for (int q = 0; q < 4; ++q) {
            const int o = wid * 64 + q * 16 + llo;
            const int bm = p * 16 + lhi * 4;
            unsigned short t4[4] = {f2bfu(acc1[p][q][0]), f2bfu(acc1[p][q][1]),
                                    f2bfu(acc1[p][q][2]), f2bfu(acc1[p][q][3])};
            *(us4*)&stm[o * 64 + (bm ^ ((o & 7) << 3))] = *(const us4*)t4;
        }

    // ---- G2: out = Ahat @ tmp2; A-frags from global Ahat (8 KB, L1-hot) ----
    f32x4 acc2[4][4];
#pragma unroll
    for (int p = 0; p < 4; ++p)
#pragma unroll
        for (int q = 0; q < 4; ++q) acc2[p][q] = (f32x4){0.f, 0.f, 0.f, 0.f};
#pragma unroll
    for (int s = 0; s < 2; ++s) {
        const int k0 = s * 32 + lhi * 8;
        short8 af[4], bf[4];
#pragma unroll
        for (int p = 0; p < 4; ++p) {
            const int n = p * 16 + llo;
            af[p] = *(const short8*)&Ahat[n * 64 + k0];
        }
#pragma unroll
        for (int q = 0; q < 4; ++q) {
            const int o = wid * 64 + q * 16 + llo;
            bf[q] = *(const short8*)&stm[o * 64 + (k0 ^ ((o & 7) << 3))];
        }
#pragma unroll
        for (int p = 0; p < 4; ++p)
#pragma unroll
            for (int q = 0; q < 4; ++q)
                acc2[p][q] = __builtin_amdgcn_mfma_f32_16x16x32_bf16(af[p], bf[q], acc2[p][q], 0, 0, 0);
    }

    // ---- epilogue: +bgcn, bf16 scatter to [n][b][o] (512B runs per n; L2 merges) ----
    float bg[4];
#pragma unroll
    for (int q = 0; q < 4; ++q) bg[q] = bgcn[wid * 64 + q * 16 + llo];
#pragma unroll
    for (int p = 0; p < 4; ++p)
#pragma unroll
        for (int q = 0; q < 4; ++q) {
            const int o = wid * 64 + q * 16 + llo;
#pragma unroll
            for (int reg = 0; reg < 4; ++reg) {
                const int n = p * 16 + lhi * 4 + reg;
                xgcn[((size_t)n * BB + b) * CO + o] = f2bfu(acc2[p][q][reg] + bg[q]);
            }
        }
}

// ---------------- kernel 4: conv1d-as-GEMM, whole-A-slab in LDS, B from L2, barrier-free K-loop ----------------
// Per (tt, ot, n): C[t][o] = sum_{kk,c} A[t+kk-1][c] * W2t[o][kk*256+c]
__global__ __launch_bounds__(256) void k_conv(const __hip_bfloat16* __restrict__ xgcn_,
                                              const __hip_bfloat16* __restrict__ W2t_,
                                              const float* __restrict__ bconv,
                                              __hip_bfloat16* __restrict__ y_,
                                              float* __restrict__ partials) {
    __shared__ __align__(16) unsigned short sA[130 * 256];   // 66.5 KB: rows t0-1..t0+128, granule-swizzled
    const unsigned short* xgcn = (const unsigned short*)xgcn_;
    const unsigned short* W2t  = (const unsigned short*)W2t_;
    unsigned short* y = (unsigned short*)y_;

    const int tt = blockIdx.x, ot = blockIdx.y, n = blockIdx.z;
    const int tid = threadIdx.x;
    const int lane = tid & 63, wid = tid >> 6;
    const int t0 = tt * 128, o0 = ot * 128;
    const int wm0 = (wid >> 1) * 64, wn0 = (wid & 1) * 64;
    const int lhi = lane >> 4, llo = lane & 15;

    f32x4 acc[4][4];
#pragma unroll
    for (int m = 0; m < 4; ++m)
#pragma unroll
        for (int nn = 0; nn < 4; ++nn) acc[m][nn] = (f32x4){0.f, 0.f, 0.f, 0.f};

    // ---- stage whole A slab: 65 issues x 1KB (2 rows each), coalesced from [n][b][c] layout ----
    // dest linear; source granule pre-swizzled: LDS[r][g] holds global cols ((g^(r&7))*8..+8)
    {
        const int rsub = lane >> 5;                 // 0,1: row within issue
        const int g = lane & 31;                    // 16B granule within row
        for (int iss = wid; iss < 65; iss += 4) {
            const int r = 2 * iss + rsub;
            int bg = t0 - 1 + r;
            bg = min(max(bg, 0), BB - 1);           // clamped; halo rows zeroed below
            const int col = ((g ^ (r & 7)) << 3);
            gload_lds16(xgcn + ((size_t)n * BB + bg) * CO + col, sA + iss * 512);
        }
    }
    __syncthreads();   // drains vmcnt(0): slab complete
    if (tt == 0 || tt == 15) {                      // halo row zero (block-uniform branch)
        const int zr = (tt == 0) ? 0 : 129;
        if (tid < 32) *(uint4*)&sA[zr * 256 + tid * 8] = make_uint4(0u, 0u, 0u, 0u);
        __syncthreads();
    }

    // ---- K-loop: 24 steps x 16 MFMA, NO barriers; B-frags straight from global (L1/L2-hot) ----
#pragma unroll 8
    for (int kc = 0; kc < 24; ++kc) {
        const int kk = kc >> 3;                     // conv tap 0..2
        const int G = (kc & 7) * 4 + lhi;           // 16B granule within 256-ch row
        short8 af[4], bf[4];
#pragma unroll
        for (int m = 0; m < 4; ++m) {
            const int sr = wm0 + m * 16 + llo + kk; // slab row (t+kk-1 shift)
            af[m] = *(const short8*)&sA[sr * 256 + ((G ^ (sr & 7)) << 3)];
        }
#pragma unroll
        for (int q = 0; q < 4; ++q) {
            const int o = o0 + wn0 + q * 16 + llo;
            bf[q] = *(const short8*)&W2t[o * 768 + kk * 256 + (kc & 7) * 32 + lhi * 8];
        }
#pragma unroll
        for (int m = 0; m < 4; ++m)
#pragma unroll
            for (int q = 0; q < 4; ++q)
                acc[m][q] = __builtin_amdgcn_mfma_f32_16x16x32_bf16(af[m], bf[q], acc[m][q], 0, 0, 0);
    }

    // ---- epilogue: +bias, store y bf16 [t][n][o], per-block BN partials (f32-exact) ----
    float bc[4], s1v[4], s2v[4];
#pragma unroll
    for (int nn = 0; nn < 4; ++nn) {
        bc[nn] = bconv[o0 + wn0 + nn * 16 + llo];
        s1v[nn] = 0.f; s2v[nn] = 0.f;
    }
#pragma unroll
    for (int m = 0; m < 4; ++m) {
#pragma unroll
        for (int reg = 0; reg < 4; ++reg) {
            const int trow = t0 + wm0 + m * 16 + lhi * 4 + reg;
            unsigned short* dst = y + ((size_t)trow * NN + n) * CO + o0 + wn0 + llo;
#pragma unroll
            for (int nn = 0; nn < 4; ++nn) {
                const float v = acc[m][nn][reg] + bc[nn];
                dst[nn * 16] = f2bfu(v);
                s1v[nn] += v;
                s2v[nn] += v * v;
            }
        }
    }
    __syncthreads();   // all waves done reading sA before reuse as reduction scratch
    float* sred1 = (float*)sA;          // [8][128]
    float* sred2 = sred1 + 1024;
    const int rg = (wid >> 1) * 4 + lhi;
#pragma unroll
    for (int nn = 0; nn < 4; ++nn) {
        const int cl = wn0 + nn * 16 + llo;
        sred1[rg * 128 + cl] = s1v[nn];
        sred2[rg * 128 + cl] = s2v[nn];
    }
    __syncthreads();
    if (tid < 128) {
        float a = 0.f, b2 = 0.f;
#pragma unroll
        for (int r = 0; r < 8; ++r) { a += sred1[r * 128 + tid]; b2 += sred2[r * 128 + tid]; }
        float* pb = partials + (size_t)((n * 2 + ot) * 16 + tt) * 256;
        pb[tid * 2]     = a;
        pb[tid * 2 + 1] = b2;
    }
}

// ---------------- kernel 5: reduce BN partials -> scale/shift per channel ----------------
__global__ __launch_bounds__(256) void k_bnstats(const float* __restrict__ partials,
                                                 const float* __restrict__ gamma,
                                                 const float* __restrict__ beta,
                                                 float* __restrict__ scl,
                                                 float* __restrict__ shf) {
    const int o = blockIdx.x, tid = threadIdx.x;
    const int ot = o >> 7, c = o & 127;
    float s1 = 0.f, s2 = 0.f;
    for (int i = tid; i < 1024; i += 256) {
        const int nn = i >> 4, tt = i & 15;
        const float* p = partials + ((size_t)((nn * 2 + ot) * 16 + tt)) * 256 + c * 2;
        s1 += p[0]; s2 += p[1];
    }
    __shared__ float r1[256], r2[256];
    r1[tid] = s1; r2[tid] = s2;
    __syncthreads();
    for (int s = 128; s > 0; s >>= 1) {
        if (tid < s) { r1[tid] += r1[tid + s]; r2[tid] += r2[tid + s]; }
        __syncthreads();
    }
    if (tid == 0) {
        const float inv = 1.f / (float)((size_t)BB * NN);
        const float mean = r1[0] * inv;
        const float var  = r2[0] * inv - mean * mean;
        const float sc = gamma[o] * rsqrtf(var + EPSBN);
        scl[o] = sc;
        shf[o] = beta[o] - mean * sc;
    }
}

// ---------------- kernel 6: BN apply + ReLU: y bf16 -> out f32 ----------------
__global__ __launch_bounds__(256) void k_apply(const unsigned short* __restrict__ y,
                                               float* __restrict__ out,
                                               const float* __restrict__ scl,
                                               const float* __restrict__ shf) {
    __shared__ float ssc[CO], ssh[CO];
    const int tid = threadIdx.x;
    ssc[tid] = scl[tid]; ssh[tid] = shf[tid];
    __syncthreads();
    const size_t total8 = (size_t)BB * NN * CO / 8;
    float4* out4 = (float4*)out;
    for (size_t i = (size_t)blockIdx.x * 256 + tid; i < total8; i += (size_t)gridDim.x * 256) {
        const us8 v = *(const us8*)(y + i * 8);
        const int ob = (int)((i * 8) & (CO - 1));
        float4 r0, r1;
        r0.x = fmaxf(0.f, bf2f(v[0]) * ssc[ob + 0] + ssh[ob + 0]);
        r0.y = fmaxf(0.f, bf2f(v[1]) * ssc[ob + 1] + ssh[ob + 1]);
        r0.z = fmaxf(0.f, bf2f(v[2]) * ssc[ob + 2] + ssh[ob + 2]);
        r0.w = fmaxf(0.f, bf2f(v[3]) * ssc[ob + 3] + ssh[ob + 3]);
        r1.x = fmaxf(0.f, bf2f(v[4]) * ssc[ob + 4] + ssh[ob + 4]);
        r1.y = fmaxf(0.f, bf2f(v[5]) * ssc[ob + 5] + ssh[ob + 5]);
        r1.z = fmaxf(0.f, bf2f(v[6]) * ssc[ob + 6] + ssh[ob + 6]);
        r1.w = fmaxf(0.f, bf2f(v[7]) * ssc[ob + 7] + ssh[ob + 7]);
        out4[i * 2]     = r0;
        out4[i * 2 + 1] = r1;
    }
}

extern "C" void kernel_launch(void* const* d_in, const int* in_sizes, int n_in,
                              void* d_out, int out_size, void* d_ws, size_t ws_size,
                              hipStream_t stream) {
    const float* x     = (const float*)d_in[0];
    const float* W     = (const float*)d_in[1];
    const float* bgcn  = (const float*)d_in[2];
    const float* wconv = (const float*)d_in[3];
    const float* bconv = (const float*)d_in[4];
    const float* gamma = (const float*)d_in[5];
    const float* beta  = (const float*)d_in[6];
    const int*   ei    = (const int*)d_in[7];
    float* out = (float*)d_out;

    char* ws = (char*)d_ws;
    size_t off = 0;
    __hip_bfloat16* xgcn = (__hip_bfloat16*)(ws + off); off += (size_t)BB * NN * CO * 2;   // 67 MB, [n][b][c]
    __hip_bfloat16* ybuf = (__hip_bfloat16*)(ws + off); off += (size_t)BB * NN * CO * 2;   // 67 MB, [b][n][o]
    __hip_bfloat16* W2t  = (__hip_bfloat16*)(ws + off); off += (size_t)CO * KWIN * CO * 2; // 384 KB
    __hip_bfloat16* Ahat = (__hip_bfloat16*)(ws + off); off += (size_t)NN * NN * 2;        // 8 KB
    __hip_bfloat16* Wt   = (__hip_bfloat16*)(ws + off); off += (size_t)CO * CIN * 2;       // 64 KB
    float* partials = (float*)(ws + off); off += (size_t)2048 * 256 * 4;                   // 2 MB
    float* scl = (float*)(ws + off); off += 256 * 4;
    float* shf = (float*)(ws + off); off += 256 * 4;

    k_setup<<<1, 320, 0, stream>>>(ei, Ahat);
    k_weights<<<896, 256, 0, stream>>>(W, wconv, Wt, W2t);
    k_gcn<<<BB, 256, 0, stream>>>(x, Ahat, Wt, bgcn, xgcn);
    k_conv<<<dim3(16, 2, 64), 256, 0, stream>>>(xgcn, W2t, bconv, ybuf, partials);
    k_bnstats<<<256, 256, 0, stream>>>(partials, gamma, beta, scl, shf);
    k_apply<<<2048, 256, 0, stream>>>((const unsigned short*)ybuf, out, scl, shf);
}

// Round 6
// 157.196 us; speedup vs baseline: 1.3315x; 1.3315x over previous
//
#include <hip/hip_runtime.h>
#include <hip/hip_bf16.h>

typedef __attribute__((ext_vector_type(8))) unsigned short us8;
typedef __attribute__((ext_vector_type(4))) unsigned short us4;
typedef __attribute__((ext_vector_type(8))) short short8;
typedef __attribute__((ext_vector_type(4))) float f32x4;

#define BB 2048
#define NN 64
#define CIN 128
#define CO 256
#define KWIN 3
#define EE 256
#define NE 320            // E + N (self loops)
#define EPSBN 1e-5f

static __device__ __forceinline__ void gload_lds16(const unsigned short* g, unsigned short* l) {
    __builtin_amdgcn_global_load_lds(
        (const __attribute__((address_space(1))) unsigned int*)g,
        (__attribute__((address_space(3))) unsigned int*)l,
        16, 0, 0);
}

static __device__ __forceinline__ float bf2f(unsigned short u) {
    return __uint_as_float(((unsigned int)u) << 16);
}

static __device__ __forceinline__ unsigned short f2bfu(float f) {
    unsigned int u = __float_as_uint(f);
    u = (u + 0x7FFFu + ((u >> 16) & 1u)) >> 16;   // RN-even
    return (unsigned short)u;
}

// ---------------- kernel 1: dense normalized adjacency Ahat[dst][src] (bf16), deterministic ----------------
__global__ __launch_bounds__(320) void k_setup(const int* __restrict__ ei,
                                               __hip_bfloat16* __restrict__ Ahat) {
    __shared__ int s_cnt[NN * NN];   // 16 KB
    __shared__ int s_deg[NN];
    __shared__ float s_dinv[NN];
    const int t = threadIdx.x;
    for (int i = t; i < NN * NN; i += 320) s_cnt[i] = 0;
    if (t < NN) s_deg[t] = 0;
    __syncthreads();
    int src, dst;
    if (t < EE) { src = ei[t]; dst = ei[EE + t]; }
    else        { src = t - EE; dst = t - EE; }
    atomicAdd(&s_deg[dst], 1);                 // integer: order-independent, deterministic
    atomicAdd(&s_cnt[dst * NN + src], 1);
    __syncthreads();
    if (t < NN) s_dinv[t] = rsqrtf((float)s_deg[t]);   // deg >= 1 (self loop)
    __syncthreads();
    for (int i = t; i < NN * NN; i += 320) {
        const int n = i >> 6, m = i & 63;
        Ahat[i] = __float2bfloat16((float)s_cnt[i] * s_dinv[m] * s_dinv[n]);
    }
}

// ---------------- kernel 2: pack weights ----------------
// Wt[o][c] = W[c][o]
// W2f fragment-packed: W2f[((o16*24 + kc)*64 + lane)*8 + e] = B[o16*16 + (lane&15)][kc*32 + (lane>>4)*8 + e]
//   where B[o][k] = wconv[o][k&255][k>>8]
__global__ __launch_bounds__(256) void k_weights(const float* __restrict__ W,
                                                 const float* __restrict__ wconv,
                                                 __hip_bfloat16* __restrict__ Wt,
                                                 __hip_bfloat16* __restrict__ W2f) {
    const int idx = blockIdx.x * 256 + threadIdx.x;
    if (idx < CO * CIN) {                                 // 32768
        const int o = idx >> 7, c = idx & 127;
        Wt[idx] = __float2bfloat16(W[c * CO + o]);
    }
    const int j = idx - CO * CIN;
    if (j >= 0 && j < CO * KWIN * CO) {                   // 196608
        const int o16 = j / 12288, r = j - o16 * 12288;   // 24*512 = 12288
        const int kc = r >> 9, r2 = r & 511;
        const int l = r2 >> 3, e = r2 & 7;
        const int o = o16 * 16 + (l & 15);
        const int k = kc * 32 + (l >> 4) * 8 + e;
        W2f[j] = __float2bfloat16(wconv[(o * CO + (k & 255)) * KWIN + (k >> 8)]);
    }
}

// ---------------- kernel 3: fused GCN via MFMA: xgcn = Ahat @ (x[b] @ W) + bgcn ----------------
// Output layout: xgcn[n][b][o]  (node-major, so conv A-stage is contiguous in b)
__global__ __launch_bounds__(256) void k_gcn(const float* __restrict__ x,
                                             const __hip_bfloat16* __restrict__ Ahat_,
                                             const __hip_bfloat16* __restrict__ Wt_,
                                             const float* __restrict__ bgcn,
                                             __hip_bfloat16* __restrict__ xgcn_) {
    __shared__ __align__(16) unsigned short sx[64 * 128];    // [m][c] swizzled, 16 KB
    __shared__ __align__(16) unsigned short stm[256 * 64];   // [o][m] swizzled, 32 KB (wave-private rows)
    const unsigned short* Ahat = (const unsigned short*)Ahat_;
    const unsigned short* Wt   = (const unsigned short*)Wt_;
    unsigned short* xgcn = (unsigned short*)xgcn_;

    const int b = blockIdx.x, tid = threadIdx.x;
    const int lane = tid & 63, wid = tid >> 6;
    const int llo = lane & 15, lhi = lane >> 4;

    // ---- stage x[b] f32 -> sx bf16 [m][c], XOR-swizzled cols, row-contiguous writes ----
#pragma unroll
    for (int r = 0; r < 4; ++r) {
        const int f = tid + 256 * r;
        const int m = f >> 4, c0 = (f & 15) * 8;
        const float4* src = (const float4*)(x + ((size_t)b * NN + m) * CIN + c0);
        const float4 v0 = src[0], v1 = src[1];
        unsigned short t8[8] = {f2bfu(v0.x), f2bfu(v0.y), f2bfu(v0.z), f2bfu(v0.w),
                                f2bfu(v1.x), f2bfu(v1.y), f2bfu(v1.z), f2bfu(v1.w)};
        *(us8*)&sx[m * 128 + (c0 ^ ((m & 7) << 3))] = *(const us8*)t8;
    }
    __syncthreads();

    // ---- G1: tmp2 = x[b] @ W; wave owns o-cols wid*64..+64 ----
    f32x4 acc1[4][4];
#pragma unroll
    for (int p = 0; p < 4; ++p)
#pragma unroll
        for (int q = 0; q < 4; ++q) acc1[p][q] = (f32x4){0.f, 0.f, 0.f, 0.f};
#pragma unroll
    for (int s = 0; s < 4; ++s) {
        const int k0 = s * 32 + lhi * 8;
        short8 af[4], bf[4];
#pragma unroll
        for (int p = 0; p < 4; ++p) {
            const int m = p * 16 + llo;
            af[p] = *(const short8*)&sx[m * 128 + (k0 ^ ((m & 7) << 3))];
        }
#pragma unroll
        for (int q = 0; q < 4; ++q) {
            const int o = wid * 64 + q * 16 + llo;
            bf[q] = *(const short8*)&Wt[o * 128 + k0];   // global, L2-hot
        }
#pragma unroll
        for (int p = 0; p < 4; ++p)
#pragma unroll
            for (int q = 0; q < 4; ++q)
                acc1[p][q] = __builtin_amdgcn_mfma_f32_16x16x32_bf16(af[p], bf[q], acc1[p][q], 0, 0, 0);
    }
    // tmp2 -> stm [o][m] swizzled; wave-private rows -> no barrier needed
#pragma unroll
    for (int p = 0; p < 4; ++p)
#pragma unroll
        for (int q = 0; q < 4; ++q) {
            const int o = wid * 64 + q * 16 + llo;
            const int bm = p * 16 + lhi * 4;
            unsigned short t4[4] = {f2bfu(acc1[p][q][0]), f2bfu(acc1[p][q][1]),
                                    f2bfu(acc1[p][q][2]), f2bfu(acc1[p][q][3])};
            *(us4*)&stm[o * 64 + (bm ^ ((o & 7) << 3))] = *(const us4*)t4;
        }

    // ---- G2: out = Ahat @ tmp2; A-frags from global Ahat (8 KB, L1-hot) ----
    f32x4 acc2[4][4];
#pragma unroll
    for (int p = 0; p < 4; ++p)
#pragma unroll
        for (int q = 0; q < 4; ++q) acc2[p][q] = (f32x4){0.f, 0.f, 0.f, 0.f};
#pragma unroll
    for (int s = 0; s < 2; ++s) {
        const int k0 = s * 32 + lhi * 8;
        short8 af[4], bf[4];
#pragma unroll
        for (int p = 0; p < 4; ++p) {
            const int n = p * 16 + llo;
            af[p] = *(const short8*)&Ahat[n * 64 + k0];
        }
#pragma unroll
        for (int q = 0; q < 4; ++q) {
            const int o = wid * 64 + q * 16 + llo;
            bf[q] = *(const short8*)&stm[o * 64 + (k0 ^ ((o & 7) << 3))];
        }
#pragma unroll
        for (int p = 0; p < 4; ++p)
#pragma unroll
            for (int q = 0; q < 4; ++q)
                acc2[p][q] = __builtin_amdgcn_mfma_f32_16x16x32_bf16(af[p], bf[q], acc2[p][q], 0, 0, 0);
    }

    // ---- epilogue: +bgcn, bf16 scatter to [n][b][o] ----
    float bg[4];
#pragma unroll
    for (int q = 0; q < 4; ++q) bg[q] = bgcn[wid * 64 + q * 16 + llo];
#pragma unroll
    for (int p = 0; p < 4; ++p)
#pragma unroll
        for (int q = 0; q < 4; ++q) {
            const int o = wid * 64 + q * 16 + llo;
#pragma unroll
            for (int reg = 0; reg < 4; ++reg) {
                const int n = p * 16 + lhi * 4 + reg;
                xgcn[((size_t)n * BB + b) * CO + o] = f2bfu(acc2[p][q][reg] + bg[q]);
            }
        }
}

// ---------------- kernel 4: conv1d-as-GEMM, A-slab LDS + fragment-packed B from L2, barrier-free ----------------
// Block: (tt, n), tile 128(t) x 256(o), 8 waves (2m x 4o), each wave 64x64.
__global__ __launch_bounds__(512, 4) void k_conv(const __hip_bfloat16* __restrict__ xgcn_,
                                                 const __hip_bfloat16* __restrict__ W2f_,
                                                 const float* __restrict__ bconv,
                                                 __hip_bfloat16* __restrict__ y_,
                                                 float* __restrict__ partials) {
    __shared__ __align__(16) unsigned short sA[130 * 256];   // 66.5 KB: rows t0-1..t0+128, granule-swizzled
    const unsigned short* xgcn = (const unsigned short*)xgcn_;
    const unsigned short* W2f  = (const unsigned short*)W2f_;
    unsigned short* y = (unsigned short*)y_;

    const int tt = blockIdx.x, n = blockIdx.y;
    const int tid = threadIdx.x;
    const int lane = tid & 63, wid = tid >> 6;
    const int t0 = tt * 128;
    const int wm0 = (wid >> 2) * 64;          // m-half
    const int wo0 = (wid & 3) * 64;           // o-quad
    const int lhi = lane >> 4, llo = lane & 15;

    f32x4 acc[4][4];
#pragma unroll
    for (int m = 0; m < 4; ++m)
#pragma unroll
        for (int q = 0; q < 4; ++q) acc[m][q] = (f32x4){0.f, 0.f, 0.f, 0.f};

    // ---- stage whole A slab: 65 issues x 1KB (2 rows each), coalesced from [n][b][c] layout ----
    // dest linear; source granule pre-swizzled: LDS[r][g] holds global granule (g ^ (r&7))
    {
        const int rsub = lane >> 5;                 // 0,1: row within issue
        const int g = lane & 31;                    // 16B granule within row
        for (int iss = wid; iss < 65; iss += 8) {
            const int r = 2 * iss + rsub;
            int bg = t0 - 1 + r;
            bg = min(max(bg, 0), BB - 1);           // clamped; halo rows zeroed below
            const int col = ((g ^ (r & 7)) << 3);
            gload_lds16(xgcn + ((size_t)n * BB + bg) * CO + col, sA + iss * 512);
        }
    }
    __syncthreads();   // drains vmcnt(0): slab complete
    if (tt == 0 || tt == 15) {                      // halo row zero (block-uniform branch)
        const int zr = (tt == 0) ? 0 : 129;
        if (tid < 32) *(uint4*)&sA[zr * 256 + tid * 8] = make_uint4(0u, 0u, 0u, 0u);
        __syncthreads();
    }

    // ---- K-loop: 24 steps x 16 MFMA, NO barriers; B = coalesced 1KB fragment loads (L1/L2-hot) ----
    const unsigned short* bq[4];
#pragma unroll
    for (int q = 0; q < 4; ++q) {
        const int o16 = (wid & 3) * 4 + q;
        bq[q] = W2f + ((size_t)o16 * 24) * 512 + lane * 8;
    }
#pragma unroll 4
    for (int kc = 0; kc < 24; ++kc) {
        const int kk = kc >> 3;                     // conv tap 0..2
        const int G = (kc & 7) * 4 + lhi;           // 16B granule within 256-ch row
        short8 af[4], bf[4];
#pragma unroll
        for (int m = 0; m < 4; ++m) {
            const int sr = wm0 + m * 16 + llo + kk; // slab row (t+kk-1 shift)
            af[m] = *(const short8*)&sA[sr * 256 + ((G ^ (sr & 7)) << 3)];
        }
#pragma unroll
        for (int q = 0; q < 4; ++q)
            bf[q] = *(const short8*)(bq[q] + kc * 512);
#pragma unroll
        for (int m = 0; m < 4; ++m)
#pragma unroll
            for (int q = 0; q < 4; ++q)
                acc[m][q] = __builtin_amdgcn_mfma_f32_16x16x32_bf16(af[m], bf[q], acc[m][q], 0, 0, 0);
    }

    // ---- epilogue: +bias, store y bf16 [t][n][o], per-block BN partials (f32-exact) ----
    float bc[4], s1v[4], s2v[4];
#pragma unroll
    for (int q = 0; q < 4; ++q) {
        bc[q] = bconv[wo0 + q * 16 + llo];
        s1v[q] = 0.f; s2v[q] = 0.f;
    }
#pragma unroll
    for (int m = 0; m < 4; ++m) {
#pragma unroll
        for (int reg = 0; reg < 4; ++reg) {
            const int trow = t0 + wm0 + m * 16 + lhi * 4 + reg;
            unsigned short* dst = y + ((size_t)trow * NN + n) * CO + wo0 + llo;
#pragma unroll
            for (int q = 0; q < 4; ++q) {
                const float v = acc[m][q][reg] + bc[q];
                dst[q * 16] = f2bfu(v);
                s1v[q] += v;
                s2v[q] += v * v;
            }
        }
    }
    __syncthreads();   // all waves done reading sA before reuse as reduction scratch
    float* sred1 = (float*)sA;          // [8][256]
    float* sred2 = sred1 + 2048;        // [8][256]
    const int rg = (wid >> 2) * 4 + lhi;
#pragma unroll
    for (int q = 0; q < 4; ++q) {
        const int cl = wo0 + q * 16 + llo;
        sred1[rg * 256 + cl] = s1v[q];
        sred2[rg * 256 + cl] = s2v[q];
    }
    __syncthreads();
    if (tid < 256) {
        float a = 0.f, b2 = 0.f;
#pragma unroll
        for (int r = 0; r < 8; ++r) { a += sred1[r * 256 + tid]; b2 += sred2[r * 256 + tid]; }
        float* pb = partials + (size_t)(n * 16 + tt) * 512;
        pb[tid * 2]     = a;
        pb[tid * 2 + 1] = b2;
    }
}

// ---------------- kernel 5: reduce BN partials -> scale/shift per channel ----------------
__global__ __launch_bounds__(256) void k_bnstats(const float* __restrict__ partials,
                                                 const float* __restrict__ gamma,
                                                 const float* __restrict__ beta,
                                                 float* __restrict__ scl,
                                                 float* __restrict__ shf) {
    const int o = blockIdx.x, tid = threadIdx.x;
    float s1 = 0.f, s2 = 0.f;
    for (int i = tid; i < 1024; i += 256) {           // 64 n * 16 tt
        const float* p = partials + (size_t)i * 512 + o * 2;
        s1 += p[0]; s2 += p[1];
    }
    __shared__ float r1[256], r2[256];
    r1[tid] = s1; r2[tid] = s2;
    __syncthreads();
    for (int s = 128; s > 0; s >>= 1) {
        if (tid < s) { r1[tid] += r1[tid + s]; r2[tid] += r2[tid + s]; }
        __syncthreads();
    }
    if (tid == 0) {
        const float inv = 1.f / (float)((size_t)BB * NN);
        const float mean = r1[0] * inv;
        const float var  = r2[0] * inv - mean * mean;
        const float sc = gamma[o] * rsqrtf(var + EPSBN);
        scl[o] = sc;
        shf[o] = beta[o] - mean * sc;
    }
}

// ---------------- kernel 6: BN apply + ReLU: y bf16 -> out f32 ----------------
__global__ __launch_bounds__(256) void k_apply(const unsigned short* __restrict__ y,
                                               float* __restrict__ out,
                                               const float* __restrict__ scl,
                                               const float* __restrict__ shf) {
    __shared__ float ssc[CO], ssh[CO];
    const int tid = threadIdx.x;
    ssc[tid] = scl[tid]; ssh[tid] = shf[tid];
    __syncthreads();
    const size_t total8 = (size_t)BB * NN * CO / 8;
    float4* out4 = (float4*)out;
    for (size_t i = (size_t)blockIdx.x * 256 + tid; i < total8; i += (size_t)gridDim.x * 256) {
        const us8 v = *(const us8*)(y + i * 8);
        const int ob = (int)((i * 8) & (CO - 1));
        float4 r0, r1;
        r0.x = fmaxf(0.f, bf2f(v[0]) * ssc[ob + 0] + ssh[ob + 0]);
        r0.y = fmaxf(0.f, bf2f(v[1]) * ssc[ob + 1] + ssh[ob + 1]);
        r0.z = fmaxf(0.f, bf2f(v[2]) * ssc[ob + 2] + ssh[ob + 2]);
        r0.w = fmaxf(0.f, bf2f(v[3]) * ssc[ob + 3] + ssh[ob + 3]);
        r1.x = fmaxf(0.f, bf2f(v[4]) * ssc[ob + 4] + ssh[ob + 4]);
        r1.y = fmaxf(0.f, bf2f(v[5]) * ssc[ob + 5] + ssh[ob + 5]);
        r1.z = fmaxf(0.f, bf2f(v[6]) * ssc[ob + 6] + ssh[ob + 6]);
        r1.w = fmaxf(0.f, bf2f(v[7]) * ssc[ob + 7] + ssh[ob + 7]);
        out4[i * 2]     = r0;
        out4[i * 2 + 1] = r1;
    }
}

extern "C" void kernel_launch(void* const* d_in, const int* in_sizes, int n_in,
                              void* d_out, int out_size, void* d_ws, size_t ws_size,
                              hipStream_t stream) {
    const float* x     = (const float*)d_in[0];
    const float* W     = (const float*)d_in[1];
    const float* bgcn  = (const float*)d_in[2];
    const float* wconv = (const float*)d_in[3];
    const float* bconv = (const float*)d_in[4];
    const float* gamma = (const float*)d_in[5];
    const float* beta  = (const float*)d_in[6];
    const int*   ei    = (const int*)d_in[7];
    float* out = (float*)d_out;

    char* ws = (char*)d_ws;
    size_t off = 0;
    __hip_bfloat16* xgcn = (__hip_bfloat16*)(ws + off); off += (size_t)BB * NN * CO * 2;   // 67 MB, [n][b][c]
    __hip_bfloat16* ybuf = (__hip_bfloat16*)(ws + off); off += (size_t)BB * NN * CO * 2;   // 67 MB, [b][n][o]
    __hip_bfloat16* W2f  = (__hip_bfloat16*)(ws + off); off += (size_t)CO * KWIN * CO * 2; // 384 KB, frag-packed
    __hip_bfloat16* Ahat = (__hip_bfloat16*)(ws + off); off += (size_t)NN * NN * 2;        // 8 KB
    __hip_bfloat16* Wt   = (__hip_bfloat16*)(ws + off); off += (size_t)CO * CIN * 2;       // 64 KB
    float* partials = (float*)(ws + off); off += (size_t)1024 * 512 * 4;                   // 2 MB
    float* scl = (float*)(ws + off); off += 256 * 4;
    float* shf = (float*)(ws + off); off += 256 * 4;

    k_setup<<<1, 320, 0, stream>>>(ei, Ahat);
    k_weights<<<896, 256, 0, stream>>>(W, wconv, Wt, W2f);
    k_gcn<<<BB, 256, 0, stream>>>(x, Ahat, Wt, bgcn, xgcn);
    k_conv<<<dim3(16, 64), 512, 0, stream>>>(xgcn, W2f, bconv, ybuf, partials);
    k_bnstats<<<256, 256, 0, stream>>>(partials, gamma, beta, scl, shf);
    k_apply<<<2048, 256, 0, stream>>>((const unsigned short*)ybuf, out, scl, shf);
}

// Round 7
// 147.963 us; speedup vs baseline: 1.4146x; 1.0624x over previous
//
#include <hip/hip_runtime.h>
#include <hip/hip_bf16.h>

typedef __attribute__((ext_vector_type(8))) unsigned short us8;
typedef __attribute__((ext_vector_type(4))) unsigned short us4;
typedef __attribute__((ext_vector_type(8))) short short8;
typedef __attribute__((ext_vector_type(4))) float f32x4;

#define BB 2048
#define NN 64
#define CIN 128
#define CO 256
#define KWIN 3
#define EE 256
#define NE 320            // E + N (self loops)
#define EPSBN 1e-5f

static __device__ __forceinline__ void gload_lds16(const unsigned short* g, unsigned short* l) {
    __builtin_amdgcn_global_load_lds(
        (const __attribute__((address_space(1))) unsigned int*)g,
        (__attribute__((address_space(3))) unsigned int*)l,
        16, 0, 0);
}

static __device__ __forceinline__ float bf2f(unsigned short u) {
    return __uint_as_float(((unsigned int)u) << 16);
}

static __device__ __forceinline__ unsigned short f2bfu(float f) {
    unsigned int u = __float_as_uint(f);
    u = (u + 0x7FFFu + ((u >> 16) & 1u)) >> 16;   // RN-even
    return (unsigned short)u;
}

// ---------------- kernel 1 (merged prep): weights pack + dense adjacency ----------------
// blocks 0..895: Wt[o][c]=W[c][o]; W2f fragment-packed.
// block 896: Ahat[dst][src] deterministic (integer LDS atomics).
__global__ __launch_bounds__(256) void k_prep(const int* __restrict__ ei,
                                              const float* __restrict__ W,
                                              const float* __restrict__ wconv,
                                              __hip_bfloat16* __restrict__ Ahat,
                                              __hip_bfloat16* __restrict__ Wt,
                                              __hip_bfloat16* __restrict__ W2f) {
    __shared__ int s_cnt[NN * NN];   // used only by block 896
    __shared__ int s_deg[NN];
    __shared__ float s_dinv[NN];
    const int t = threadIdx.x;
    if (blockIdx.x == 896) {
        for (int i = t; i < NN * NN; i += 256) s_cnt[i] = 0;
        if (t < NN) s_deg[t] = 0;
        __syncthreads();
        for (int e = t; e < NE; e += 256) {
            int src, dst;
            if (e < EE) { src = ei[e]; dst = ei[EE + e]; }
            else        { src = e - EE; dst = e - EE; }
            atomicAdd(&s_deg[dst], 1);                 // integer: deterministic
            atomicAdd(&s_cnt[dst * NN + src], 1);
        }
        __syncthreads();
        if (t < NN) s_dinv[t] = rsqrtf((float)s_deg[t]);
        __syncthreads();
        for (int i = t; i < NN * NN; i += 256) {
            const int n = i >> 6, m = i & 63;
            Ahat[i] = __float2bfloat16((float)s_cnt[i] * s_dinv[m] * s_dinv[n]);
        }
        return;
    }
    const int idx = blockIdx.x * 256 + t;
    if (idx < CO * CIN) {                                 // 32768
        const int o = idx >> 7, c = idx & 127;
        Wt[idx] = __float2bfloat16(W[c * CO + o]);
    }
    const int j = idx - CO * CIN;
    if (j >= 0 && j < CO * KWIN * CO) {                   // 196608
        const int o16 = j / 12288, r = j - o16 * 12288;   // 24*512
        const int kc = r >> 9, r2 = r & 511;
        const int l = r2 >> 3, e = r2 & 7;
        const int o = o16 * 16 + (l & 15);
        const int k = kc * 32 + (l >> 4) * 8 + e;
        W2f[j] = __float2bfloat16(wconv[(o * CO + (k & 255)) * KWIN + (k >> 8)]);
    }
}

// ---------------- kernel 2: fused GCN via MFMA: xgcn = Ahat @ (x[b] @ W) + bgcn ----------------
// Output layout: xgcn[n][b][o]  (node-major, so conv A-stage is contiguous in b)
__global__ __launch_bounds__(256) void k_gcn(const float* __restrict__ x,
                                             const __hip_bfloat16* __restrict__ Ahat_,
                                             const __hip_bfloat16* __restrict__ Wt_,
                                             const float* __restrict__ bgcn,
                                             __hip_bfloat16* __restrict__ xgcn_) {
    __shared__ __align__(16) unsigned short sx[64 * 128];    // [m][c] swizzled, 16 KB
    __shared__ __align__(16) unsigned short stm[256 * 64];   // [o][m] swizzled, 32 KB (wave-private rows)
    const unsigned short* Ahat = (const unsigned short*)Ahat_;
    const unsigned short* Wt   = (const unsigned short*)Wt_;
    unsigned short* xgcn = (unsigned short*)xgcn_;

    const int b = blockIdx.x, tid = threadIdx.x;
    const int lane = tid & 63, wid = tid >> 6;
    const int llo = lane & 15, lhi = lane >> 4;

    // ---- stage x[b] f32 -> sx bf16 [m][c], XOR-swizzled cols, row-contiguous writes ----
#pragma unroll
    for (int r = 0; r < 4; ++r) {
        const int f = tid + 256 * r;
        const int m = f >> 4, c0 = (f & 15) * 8;
        const float4* src = (const float4*)(x + ((size_t)b * NN + m) * CIN + c0);
        const float4 v0 = src[0], v1 = src[1];
        unsigned short t8[8] = {f2bfu(v0.x), f2bfu(v0.y), f2bfu(v0.z), f2bfu(v0.w),
                                f2bfu(v1.x), f2bfu(v1.y), f2bfu(v1.z), f2bfu(v1.w)};
        *(us8*)&sx[m * 128 + (c0 ^ ((m & 7) << 3))] = *(const us8*)t8;
    }
    __syncthreads();

    // ---- G1: tmp2 = x[b] @ W; wave owns o-cols wid*64..+64 ----
    f32x4 acc1[4][4];
#pragma unroll
    for (int p = 0; p < 4; ++p)
#pragma unroll
        for (int q = 0; q < 4; ++q) acc1[p][q] = (f32x4){0.f, 0.f, 0.f, 0.f};
#pragma unroll
    for (int s = 0; s < 4; ++s) {
        const int k0 = s * 32 + lhi * 8;
        short8 af[4], bf[4];
#pragma unroll
        for (int p = 0; p < 4; ++p) {
            const int m = p * 16 + llo;
            af[p] = *(const short8*)&sx[m * 128 + (k0 ^ ((m & 7) << 3))];
        }
#pragma unroll
        for (int q = 0; q < 4; ++q) {
            const int o = wid * 64 + q * 16 + llo;
            bf[q] = *(const short8*)&Wt[o * 128 + k0];   // global, L2-hot
        }
#pragma unroll
        for (int p = 0; p < 4; ++p)
#pragma unroll
            for (int q = 0; q < 4; ++q)
                acc1[p][q] = __builtin_amdgcn_mfma_f32_16x16x32_bf16(af[p], bf[q], acc1[p][q], 0, 0, 0);
    }
    // tmp2 -> stm [o][m] swizzled; wave-private rows -> no barrier needed
#pragma unroll
    for (int p = 0; p < 4; ++p)
#pragma unroll
        for (int q = 0; q < 4; ++q) {
            const int o = wid * 64 + q * 16 + llo;
            const int bm = p * 16 + lhi * 4;
            unsigned short t4[4] = {f2bfu(acc1[p][q][0]), f2bfu(acc1[p][q][1]),
                                    f2bfu(acc1[p][q][2]), f2bfu(acc1[p][q][3])};
            *(us4*)&stm[o * 64 + (bm ^ ((o & 7) << 3))] = *(const us4*)t4;
        }

    // ---- G2: out = Ahat @ tmp2; A-frags from global Ahat (8 KB, L1-hot) ----
    f32x4 acc2[4][4];
#pragma unroll
    for (int p = 0; p < 4; ++p)
#pragma unroll
        for (int q = 0; q < 4; ++q) acc2[p][q] = (f32x4){0.f, 0.f, 0.f, 0.f};
#pragma unroll
    for (int s = 0; s < 2; ++s) {
        const int k0 = s * 32 + lhi * 8;
        short8 af[4], bf[4];
#pragma unroll
        for (int p = 0; p < 4; ++p) {
            const int n = p * 16 + llo;
            af[p] = *(const short8*)&Ahat[n * 64 + k0];
        }
#pragma unroll
        for (int q = 0; q < 4; ++q) {
            const int o = wid * 64 + q * 16 + llo;
            bf[q] = *(const short8*)&stm[o * 64 + (k0 ^ ((o & 7) << 3))];
        }
#pragma unroll
        for (int p = 0; p < 4; ++p)
#pragma unroll
            for (int q = 0; q < 4; ++q)
                acc2[p][q] = __builtin_amdgcn_mfma_f32_16x16x32_bf16(af[p], bf[q], acc2[p][q], 0, 0, 0);
    }

    // ---- epilogue: +bgcn, bf16 scatter to [n][b][o] ----
    float bg[4];
#pragma unroll
    for (int q = 0; q < 4; ++q) bg[q] = bgcn[wid * 64 + q * 16 + llo];
#pragma unroll
    for (int p = 0; p < 4; ++p)
#pragma unroll
        for (int q = 0; q < 4; ++q) {
            const int o = wid * 64 + q * 16 + llo;
#pragma unroll
            for (int reg = 0; reg < 4; ++reg) {
                const int n = p * 16 + lhi * 4 + reg;
                xgcn[((size_t)n * BB + b) * CO + o] = f2bfu(acc2[p][q][reg] + bg[q]);
            }
        }
}

// ---------------- kernel 3: conv1d-as-GEMM, A-slab LDS, 1m x 8o wave tiling, barrier-free ----------------
// Block: (tt, n), tile 128(t) x 256(o), 8 waves; each wave m=128, o=32 -> disjoint B footprints.
__global__ __launch_bounds__(512, 4) void k_conv(const __hip_bfloat16* __restrict__ xgcn_,
                                                 const __hip_bfloat16* __restrict__ W2f_,
                                                 const float* __restrict__ bconv,
                                                 __hip_bfloat16* __restrict__ y_,
                                                 float* __restrict__ partials) {
    __shared__ __align__(16) unsigned short sA[130 * 256];   // 66.5 KB: rows t0-1..t0+128, granule-swizzled
    const unsigned short* xgcn = (const unsigned short*)xgcn_;
    const unsigned short* W2f  = (const unsigned short*)W2f_;
    unsigned short* y = (unsigned short*)y_;

    const int tt = blockIdx.x, n = blockIdx.y;
    const int tid = threadIdx.x;
    const int lane = tid & 63, wid = tid >> 6;
    const int t0 = tt * 128;
    const int wo0 = wid * 32;                 // this wave's o-range (32 wide)
    const int lhi = lane >> 4, llo = lane & 15;

    f32x4 acc[8][2];
#pragma unroll
    for (int p = 0; p < 8; ++p)
#pragma unroll
        for (int q = 0; q < 2; ++q) acc[p][q] = (f32x4){0.f, 0.f, 0.f, 0.f};

    // ---- stage whole A slab: 65 issues x 1KB (2 rows each), coalesced from [n][b][c] layout ----
    {
        const int rsub = lane >> 5;                 // 0,1: row within issue
        const int g = lane & 31;                    // 16B granule within row
        for (int iss = wid; iss < 65; iss += 8) {
            const int r = 2 * iss + rsub;
            int bg = t0 - 1 + r;
            bg = min(max(bg, 0), BB - 1);           // clamped; halo rows zeroed below
            const int col = ((g ^ (r & 7)) << 3);
            gload_lds16(xgcn + ((size_t)n * BB + bg) * CO + col, sA + iss * 512);
        }
    }
    __syncthreads();   // drains vmcnt(0): slab complete
    if (tt == 0 || tt == 15) {                      // halo row zero (block-uniform branch)
        const int zr = (tt == 0) ? 0 : 129;
        if (tid < 32) *(uint4*)&sA[zr * 256 + tid * 8] = make_uint4(0u, 0u, 0u, 0u);
        __syncthreads();
    }

    // ---- K-loop: 24 steps x 16 MFMA, NO barriers; B = coalesced 1KB fragment loads (L1/L2-hot) ----
    const unsigned short* bq[2];
#pragma unroll
    for (int q = 0; q < 2; ++q) {
        const int o16 = wid * 2 + q;
        bq[q] = W2f + ((size_t)o16 * 24) * 512 + lane * 8;
    }
#pragma unroll 4
    for (int kc = 0; kc < 24; ++kc) {
        const int kk = kc >> 3;                     // conv tap 0..2
        const int G = (kc & 7) * 4 + lhi;           // 16B granule within 256-ch row
        short8 af[8], bf[2];
#pragma unroll
        for (int p = 0; p < 8; ++p) {
            const int sr = p * 16 + llo + kk;       // slab row (t+kk-1 shift)
            af[p] = *(const short8*)&sA[sr * 256 + ((G ^ (sr & 7)) << 3)];
        }
#pragma unroll
        for (int q = 0; q < 2; ++q)
            bf[q] = *(const short8*)(bq[q] + kc * 512);
        __builtin_amdgcn_s_setprio(1);
#pragma unroll
        for (int p = 0; p < 8; ++p)
#pragma unroll
            for (int q = 0; q < 2; ++q)
                acc[p][q] = __builtin_amdgcn_mfma_f32_16x16x32_bf16(af[p], bf[q], acc[p][q], 0, 0, 0);
        __builtin_amdgcn_s_setprio(0);
    }

    // ---- epilogue: +bias, store y bf16 [t][n][o], per-block BN partials (f32-exact) ----
    float bc[2], s1v[2], s2v[2];
#pragma unroll
    for (int q = 0; q < 2; ++q) {
        bc[q] = bconv[wo0 + q * 16 + llo];
        s1v[q] = 0.f; s2v[q] = 0.f;
    }
#pragma unroll
    for (int p = 0; p < 8; ++p) {
#pragma unroll
        for (int reg = 0; reg < 4; ++reg) {
            const int trow = t0 + p * 16 + lhi * 4 + reg;
            unsigned short* dst = y + ((size_t)trow * NN + n) * CO + wo0 + llo;
#pragma unroll
            for (int q = 0; q < 2; ++q) {
                const float v = acc[p][q][reg] + bc[q];
                dst[q * 16] = f2bfu(v);
                s1v[q] += v;
                s2v[q] += v * v;
            }
        }
    }
    __syncthreads();   // all waves done reading sA before reuse as reduction scratch
    float* sred1 = (float*)sA;          // [4][256] (lhi-major)
    float* sred2 = sred1 + 1024;        // [4][256]
#pragma unroll
    for (int q = 0; q < 2; ++q) {
        const int cl = wo0 + q * 16 + llo;
        sred1[lhi * 256 + cl] = s1v[q];
        sred2[lhi * 256 + cl] = s2v[q];
    }
    __syncthreads();
    if (tid < 256) {
        float a = 0.f, b2 = 0.f;
#pragma unroll
        for (int r = 0; r < 4; ++r) { a += sred1[r * 256 + tid]; b2 += sred2[r * 256 + tid]; }
        float* pb = partials + (size_t)(n * 16 + tt) * 512;
        pb[tid * 2]     = a;
        pb[tid * 2 + 1] = b2;
    }
}

// ---------------- kernel 4: reduce BN partials -> scale/shift per channel ----------------
__global__ __launch_bounds__(256) void k_bnstats(const float* __restrict__ partials,
                                                 const float* __restrict__ gamma,
                                                 const float* __restrict__ beta,
                                                 float* __restrict__ scl,
                                                 float* __restrict__ shf) {
    const int o = blockIdx.x, tid = threadIdx.x;
    float s1 = 0.f, s2 = 0.f;
    for (int i = tid; i < 1024; i += 256) {           // 64 n * 16 tt
        const float* p = partials + (size_t)i * 512 + o * 2;
        s1 += p[0]; s2 += p[1];
    }
    __shared__ float r1[256], r2[256];
    r1[tid] = s1; r2[tid] = s2;
    __syncthreads();
    for (int s = 128; s > 0; s >>= 1) {
        if (tid < s) { r1[tid] += r1[tid + s]; r2[tid] += r2[tid + s]; }
        __syncthreads();
    }
    if (tid == 0) {
        const float inv = 1.f / (float)((size_t)BB * NN);
        const float mean = r1[0] * inv;
        const float var  = r2[0] * inv - mean * mean;
        const float sc = gamma[o] * rsqrtf(var + EPSBN);
        scl[o] = sc;
        shf[o] = beta[o] - mean * sc;
    }
}

// ---------------- kernel 5: BN apply + ReLU: y bf16 -> out f32 ----------------
__global__ __launch_bounds__(256) void k_apply(const unsigned short* __restrict__ y,
                                               float* __restrict__ out,
                                               const float* __restrict__ scl,
                                               const float* __restrict__ shf) {
    __shared__ float ssc[CO], ssh[CO];
    const int tid = threadIdx.x;
    ssc[tid] = scl[tid]; ssh[tid] = shf[tid];
    __syncthreads();
    const size_t total8 = (size_t)BB * NN * CO / 8;
    float4* out4 = (float4*)out;
    for (size_t i = (size_t)blockIdx.x * 256 + tid; i < total8; i += (size_t)gridDim.x * 256) {
        const us8 v = *(const us8*)(y + i * 8);
        const int ob = (int)((i * 8) & (CO - 1));
        float4 r0, r1;
        r0.x = fmaxf(0.f, bf2f(v[0]) * ssc[ob + 0] + ssh[ob + 0]);
        r0.y = fmaxf(0.f, bf2f(v[1]) * ssc[ob + 1] + ssh[ob + 1]);
        r0.z = fmaxf(0.f, bf2f(v[2]) * ssc[ob + 2] + ssh[ob + 2]);
        r0.w = fmaxf(0.f, bf2f(v[3]) * ssc[ob + 3] + ssh[ob + 3]);
        r1.x = fmaxf(0.f, bf2f(v[4]) * ssc[ob + 4] + ssh[ob + 4]);
        r1.y = fmaxf(0.f, bf2f(v[5]) * ssc[ob + 5] + ssh[ob + 5]);
        r1.z = fmaxf(0.f, bf2f(v[6]) * ssc[ob + 6] + ssh[ob + 6]);
        r1.w = fmaxf(0.f, bf2f(v[7]) * ssc[ob + 7] + ssh[ob + 7]);
        out4[i * 2]     = r0;
        out4[i * 2 + 1] = r1;
    }
}

extern "C" void kernel_launch(void* const* d_in, const int* in_sizes, int n_in,
                              void* d_out, int out_size, void* d_ws, size_t ws_size,
                              hipStream_t stream) {
    const float* x     = (const float*)d_in[0];
    const float* W     = (const float*)d_in[1];
    const float* bgcn  = (const float*)d_in[2];
    const float* wconv = (const float*)d_in[3];
    const float* bconv = (const float*)d_in[4];
    const float* gamma = (const float*)d_in[5];
    const float* beta  = (const float*)d_in[6];
    const int*   ei    = (const int*)d_in[7];
    float* out = (float*)d_out;

    char* ws = (char*)d_ws;
    size_t off = 0;
    __hip_bfloat16* xgcn = (__hip_bfloat16*)(ws + off); off += (size_t)BB * NN * CO * 2;   // 67 MB, [n][b][c]
    __hip_bfloat16* ybuf = (__hip_bfloat16*)(ws + off); off += (size_t)BB * NN * CO * 2;   // 67 MB, [b][n][o]
    __hip_bfloat16* W2f  = (__hip_bfloat16*)(ws + off); off += (size_t)CO * KWIN * CO * 2; // 384 KB, frag-packed
    __hip_bfloat16* Ahat = (__hip_bfloat16*)(ws + off); off += (size_t)NN * NN * 2;        // 8 KB
    __hip_bfloat16* Wt   = (__hip_bfloat16*)(ws + off); off += (size_t)CO * CIN * 2;       // 64 KB
    float* partials = (float*)(ws + off); off += (size_t)1024 * 512 * 4;                   // 2 MB
    float* scl = (float*)(ws + off); off += 256 * 4;
    float* shf = (float*)(ws + off); off += 256 * 4;

    k_prep<<<897, 256, 0, stream>>>(ei, W, wconv, Ahat, Wt, W2f);
    k_gcn<<<BB, 256, 0, stream>>>(x, Ahat, Wt, bgcn, xgcn);
    k_conv<<<dim3(16, 64), 512, 0, stream>>>(xgcn, W2f, bconv, ybuf, partials);
    k_bnstats<<<256, 256, 0, stream>>>(partials, gamma, beta, scl, shf);
    k_apply<<<2048, 256, 0, stream>>>((const unsigned short*)ybuf, out, scl, shf);
}

// Round 8
// 143.659 us; speedup vs baseline: 1.4570x; 1.0300x over previous
//
#include <hip/hip_runtime.h>
#include <hip/hip_bf16.h>

typedef __attribute__((ext_vector_type(8))) unsigned short us8;
typedef __attribute__((ext_vector_type(4))) unsigned short us4;
typedef __attribute__((ext_vector_type(8))) short short8;
typedef __attribute__((ext_vector_type(4))) float f32x4;

#define BB 2048
#define NN 64
#define CIN 128
#define CO 256
#define KWIN 3
#define EE 256
#define NE 320            // E + N (self loops)
#define EPSBN 1e-5f

static __device__ __forceinline__ void gload_lds16(const unsigned short* g, unsigned short* l) {
    __builtin_amdgcn_global_load_lds(
        (const __attribute__((address_space(1))) unsigned int*)g,
        (__attribute__((address_space(3))) unsigned int*)l,
        16, 0, 0);
}

static __device__ __forceinline__ float bf2f(unsigned short u) {
    return __uint_as_float(((unsigned int)u) << 16);
}

static __device__ __forceinline__ unsigned short f2bfu(float f) {
    unsigned int u = __float_as_uint(f);
    u = (u + 0x7FFFu + ((u >> 16) & 1u)) >> 16;   // RN-even
    return (unsigned short)u;
}

// ---------------- kernel 1 (merged prep): weights pack + dense adjacency ----------------
// blocks 0..895: Wtf (frag-packed W^T) + W2f (frag-packed conv weights).
// block 896: Ahat[dst][src] deterministic (integer LDS atomics).
// Wtf[((o16*4 + s)*64 + l)*8 + e] = W[(s*32+(l>>4)*8+e)][o16*16+(l&15)]
// W2f[((o16*24 + kc)*64 + l)*8 + e] = B[o16*16+(l&15)][kc*32+(l>>4)*8+e], B[o][k]=wconv[o][k&255][k>>8]
__global__ __launch_bounds__(256) void k_prep(const int* __restrict__ ei,
                                              const float* __restrict__ W,
                                              const float* __restrict__ wconv,
                                              __hip_bfloat16* __restrict__ Ahat,
                                              __hip_bfloat16* __restrict__ Wtf,
                                              __hip_bfloat16* __restrict__ W2f) {
    __shared__ int s_cnt[NN * NN];   // used only by block 896
    __shared__ int s_deg[NN];
    __shared__ float s_dinv[NN];
    const int t = threadIdx.x;
    if (blockIdx.x == 896) {
        for (int i = t; i < NN * NN; i += 256) s_cnt[i] = 0;
        if (t < NN) s_deg[t] = 0;
        __syncthreads();
        for (int e = t; e < NE; e += 256) {
            int src, dst;
            if (e < EE) { src = ei[e]; dst = ei[EE + e]; }
            else        { src = e - EE; dst = e - EE; }
            atomicAdd(&s_deg[dst], 1);                 // integer: deterministic
            atomicAdd(&s_cnt[dst * NN + src], 1);
        }
        __syncthreads();
        if (t < NN) s_dinv[t] = rsqrtf((float)s_deg[t]);
        __syncthreads();
        for (int i = t; i < NN * NN; i += 256) {
            const int n = i >> 6, m = i & 63;
            Ahat[i] = __float2bfloat16((float)s_cnt[i] * s_dinv[m] * s_dinv[n]);
        }
        return;
    }
    const int idx = blockIdx.x * 256 + t;
    if (idx < CO * CIN) {                                 // 32768: Wtf
        const int o16 = idx >> 11, s = (idx >> 9) & 3;
        const int l = (idx >> 3) & 63, e = idx & 7;
        const int o = o16 * 16 + (l & 15);
        const int c = s * 32 + (l >> 4) * 8 + e;
        Wtf[idx] = __float2bfloat16(W[c * CO + o]);
    }
    const int j = idx - CO * CIN;
    if (j >= 0 && j < CO * KWIN * CO) {                   // 196608: W2f
        const int o16 = j / 12288, r = j - o16 * 12288;   // 24*512
        const int kc = r >> 9, r2 = r & 511;
        const int l = r2 >> 3, e = r2 & 7;
        const int o = o16 * 16 + (l & 15);
        const int k = kc * 32 + (l >> 4) * 8 + e;
        W2f[j] = __float2bfloat16(wconv[(o * CO + (k & 255)) * KWIN + (k >> 8)]);
    }
}

// ---------------- kernel 2: fused GCN via MFMA: xgcn = Ahat @ (x[b] @ W) + bgcn ----------------
// G1: tmp2[m][o] = sum_c x[b][m][c] Wtf-frags   (B coalesced 1KB loads, L1-hot)
// G2: out[n][o]  = sum_m Ahat[n][m] tmp2[m][o]
// Output layout: xgcn[n][b][o]  (node-major, so conv A-stage is contiguous in b)
__global__ __launch_bounds__(256) void k_gcn(const float* __restrict__ x,
                                             const __hip_bfloat16* __restrict__ Ahat_,
                                             const __hip_bfloat16* __restrict__ Wtf_,
                                             const float* __restrict__ bgcn,
                                             __hip_bfloat16* __restrict__ xgcn_) {
    __shared__ __align__(16) unsigned short sx[64 * 128];    // [m][c] swizzled, 16 KB
    __shared__ __align__(16) unsigned short stm[256 * 64];   // [o][m] swizzled, 32 KB (wave-private rows)
    const unsigned short* Ahat = (const unsigned short*)Ahat_;
    const unsigned short* Wtf  = (const unsigned short*)Wtf_;
    unsigned short* xgcn = (unsigned short*)xgcn_;

    const int b = blockIdx.x, tid = threadIdx.x;
    const int lane = tid & 63, wid = tid >> 6;
    const int llo = lane & 15, lhi = lane >> 4;

    // ---- stage x[b] f32 -> sx bf16 [m][c], XOR-swizzled cols, row-contiguous writes ----
#pragma unroll
    for (int r = 0; r < 4; ++r) {
        const int f = tid + 256 * r;
        const int m = f >> 4, c0 = (f & 15) * 8;
        const float4* src = (const float4*)(x + ((size_t)b * NN + m) * CIN + c0);
        const float4 v0 = src[0], v1 = src[1];
        unsigned short t8[8] = {f2bfu(v0.x), f2bfu(v0.y), f2bfu(v0.z), f2bfu(v0.w),
                                f2bfu(v1.x), f2bfu(v1.y), f2bfu(v1.z), f2bfu(v1.w)};
        *(us8*)&sx[m * 128 + (c0 ^ ((m & 7) << 3))] = *(const us8*)t8;
    }
    __syncthreads();

    // ---- G1: tmp2 = x[b] @ W; wave owns o-cols wid*64..+64 (o16-tiles wid*4..+4) ----
    f32x4 acc1[4][4];
#pragma unroll
    for (int p = 0; p < 4; ++p)
#pragma unroll
        for (int q = 0; q < 4; ++q) acc1[p][q] = (f32x4){0.f, 0.f, 0.f, 0.f};
#pragma unroll
    for (int s = 0; s < 4; ++s) {
        const int k0 = s * 32 + lhi * 8;
        short8 af[4], bf[4];
#pragma unroll
        for (int p = 0; p < 4; ++p) {
            const int m = p * 16 + llo;
            af[p] = *(const short8*)&sx[m * 128 + (k0 ^ ((m & 7) << 3))];
        }
#pragma unroll
        for (int q = 0; q < 4; ++q)
            bf[q] = *(const short8*)&Wtf[(((wid * 4 + q) * 4 + s) * 64 + lane) * 8];
#pragma unroll
        for (int p = 0; p < 4; ++p)
#pragma unroll
            for (int q = 0; q < 4; ++q)
                acc1[p][q] = __builtin_amdgcn_mfma_f32_16x16x32_bf16(af[p], bf[q], acc1[p][q], 0, 0, 0);
    }
    // tmp2 -> stm [o][m] swizzled; wave-private rows -> no barrier needed
#pragma unroll
    for (int p = 0; p < 4; ++p)
#pragma unroll
        for (int q = 0; q < 4; ++q) {
            const int o = wid * 64 + q * 16 + llo;
            const int bm = p * 16 + lhi * 4;
            unsigned short t4[4] = {f2bfu(acc1[p][q][0]), f2bfu(acc1[p][q][1]),
                                    f2bfu(acc1[p][q][2]), f2bfu(acc1[p][q][3])};
            *(us4*)&stm[o * 64 + (bm ^ ((o & 7) << 3))] = *(const us4*)t4;
        }

    // ---- G2: out = Ahat @ tmp2; A-frags from global Ahat (8 KB, L1-hot) ----
    f32x4 acc2[4][4];
#pragma unroll
    for (int p = 0; p < 4; ++p)
#pragma unroll
        for (int q = 0; q < 4; ++q) acc2[p][q] = (f32x4){0.f, 0.f, 0.f, 0.f};
#pragma unroll
    for (int s = 0; s < 2; ++s) {
        const int k0 = s * 32 + lhi * 8;
        short8 af[4], bf[4];
#pragma unroll
        for (int p = 0; p < 4; ++p) {
            const int n = p * 16 + llo;
            af[p] = *(const short8*)&Ahat[n * 64 + k0];
        }
#pragma unroll
        for (int q = 0; q < 4; ++q) {
            const int o = wid * 64 + q * 16 + llo;
            bf[q] = *(const short8*)&stm[o * 64 + (k0 ^ ((o & 7) << 3))];
        }
#pragma unroll
        for (int p = 0; p < 4; ++p)
#pragma unroll
            for (int q = 0; q < 4; ++q)
                acc2[p][q] = __builtin_amdgcn_mfma_f32_16x16x32_bf16(af[p], bf[q], acc2[p][q], 0, 0, 0);
    }

    // ---- epilogue: +bgcn, bf16 scatter to [n][b][o] ----
    float bg[4];
#pragma unroll
    for (int q = 0; q < 4; ++q) bg[q] = bgcn[wid * 64 + q * 16 + llo];
#pragma unroll
    for (int p = 0; p < 4; ++p)
#pragma unroll
        for (int q = 0; q < 4; ++q) {
            const int o = wid * 64 + q * 16 + llo;
#pragma unroll
            for (int reg = 0; reg < 4; ++reg) {
                const int n = p * 16 + lhi * 4 + reg;
                xgcn[((size_t)n * BB + b) * CO + o] = f2bfu(acc2[p][q][reg] + bg[q]);
            }
        }
}

// ---------------- kernel 3: conv1d-as-GEMM, A-slab LDS, 2m x 4o wave tiling, barrier-free ----------------
// Block: (tt, n), tile 128(t) x 256(o), 8 waves; wave (wm, wo4): m = wm*64..+64, o = wo4*64..+64.
__global__ __launch_bounds__(512, 4) void k_conv(const __hip_bfloat16* __restrict__ xgcn_,
                                                 const __hip_bfloat16* __restrict__ W2f_,
                                                 const float* __restrict__ bconv,
                                                 __hip_bfloat16* __restrict__ y_,
                                                 float* __restrict__ partials) {
    __shared__ __align__(16) unsigned short sA[130 * 256];   // 66.5 KB: rows t0-1..t0+128, granule-swizzled
    const unsigned short* xgcn = (const unsigned short*)xgcn_;
    const unsigned short* W2f  = (const unsigned short*)W2f_;
    unsigned short* y = (unsigned short*)y_;

    const int tt = blockIdx.x, n = blockIdx.y;
    const int tid = threadIdx.x;
    const int lane = tid & 63, wid = tid >> 6;
    const int t0 = tt * 128;
    const int wm = wid >> 2, wo4 = wid & 3;
    const int wm0 = wm * 64, wo0 = wo4 * 64;
    const int lhi = lane >> 4, llo = lane & 15;

    f32x4 acc[4][4];
#pragma unroll
    for (int p = 0; p < 4; ++p)
#pragma unroll
        for (int q = 0; q < 4; ++q) acc[p][q] = (f32x4){0.f, 0.f, 0.f, 0.f};

    // ---- stage whole A slab: 65 issues x 1KB (2 rows each), coalesced from [n][b][c] layout ----
    {
        const int rsub = lane >> 5;                 // 0,1: row within issue
        const int g = lane & 31;                    // 16B granule within row
        for (int iss = wid; iss < 65; iss += 8) {
            const int r = 2 * iss + rsub;
            int bg = t0 - 1 + r;
            bg = min(max(bg, 0), BB - 1);           // clamped; halo rows zeroed below
            const int col = ((g ^ (r & 7)) << 3);
            gload_lds16(xgcn + ((size_t)n * BB + bg) * CO + col, sA + iss * 512);
        }
    }
    __syncthreads();   // drains vmcnt(0): slab complete
    if (tt == 0 || tt == 15) {                      // halo row zero (block-uniform branch)
        const int zr = (tt == 0) ? 0 : 129;
        if (tid < 32) *(uint4*)&sA[zr * 256 + tid * 8] = make_uint4(0u, 0u, 0u, 0u);
        __syncthreads();
    }

    // ---- K-loop: 24 steps x 16 MFMA, NO barriers; B = coalesced 1KB fragment loads (L1/L2-hot) ----
    const unsigned short* bq[4];
#pragma unroll
    for (int q = 0; q < 4; ++q) {
        const int o16 = wo4 * 4 + q;
        bq[q] = W2f + ((size_t)o16 * 24) * 512 + lane * 8;
    }
#pragma unroll 4
    for (int kc = 0; kc < 24; ++kc) {
        const int kk = kc >> 3;                     // conv tap 0..2
        const int G = (kc & 7) * 4 + lhi;           // 16B granule within 256-ch row
        short8 af[4], bf[4];
#pragma unroll
        for (int p = 0; p < 4; ++p) {
            const int sr = wm0 + p * 16 + llo + kk; // slab row (t+kk-1 shift)
            af[p] = *(const short8*)&sA[sr * 256 + ((G ^ (sr & 7)) << 3)];
        }
#pragma unroll
        for (int q = 0; q < 4; ++q)
            bf[q] = *(const short8*)(bq[q] + kc * 512);
        __builtin_amdgcn_s_setprio(1);
#pragma unroll
        for (int p = 0; p < 4; ++p)
#pragma unroll
            for (int q = 0; q < 4; ++q)
                acc[p][q] = __builtin_amdgcn_mfma_f32_16x16x32_bf16(af[p], bf[q], acc[p][q], 0, 0, 0);
        __builtin_amdgcn_s_setprio(0);
    }

    // ---- epilogue: +bias, store y bf16 [t][n][o], per-block BN partials (f32-exact) ----
    float bc[4], s1v[4], s2v[4];
#pragma unroll
    for (int q = 0; q < 4; ++q) {
        bc[q] = bconv[wo0 + q * 16 + llo];
        s1v[q] = 0.f; s2v[q] = 0.f;
    }
#pragma unroll
    for (int p = 0; p < 4; ++p) {
#pragma unroll
        for (int reg = 0; reg < 4; ++reg) {
            const int trow = t0 + wm0 + p * 16 + lhi * 4 + reg;
            unsigned short* dst = y + ((size_t)trow * NN + n) * CO + wo0 + llo;
#pragma unroll
            for (int q = 0; q < 4; ++q) {
                const float v = acc[p][q][reg] + bc[q];
                dst[q * 16] = f2bfu(v);
                s1v[q] += v;
                s2v[q] += v * v;
            }
        }
    }
    __syncthreads();   // all waves done reading sA before reuse as reduction scratch
    float* sred1 = (float*)sA;          // [8][256]
    float* sred2 = sred1 + 2048;        // [8][256]
    const int rg = wm * 4 + lhi;
#pragma unroll
    for (int q = 0; q < 4; ++q) {
        const int cl = wo0 + q * 16 + llo;
        sred1[rg * 256 + cl] = s1v[q];
        sred2[rg * 256 + cl] = s2v[q];
    }
    __syncthreads();
    if (tid < 256) {
        float a = 0.f, b2 = 0.f;
#pragma unroll
        for (int r = 0; r < 8; ++r) { a += sred1[r * 256 + tid]; b2 += sred2[r * 256 + tid]; }
        float* pb = partials + (size_t)(n * 16 + tt) * 512;
        pb[tid * 2]     = a;
        pb[tid * 2 + 1] = b2;
    }
}

// ---------------- kernel 4: reduce BN partials -> scale/shift per channel ----------------
__global__ __launch_bounds__(256) void k_bnstats(const float* __restrict__ partials,
                                                 const float* __restrict__ gamma,
                                                 const float* __restrict__ beta,
                                                 float* __restrict__ scl,
                                                 float* __restrict__ shf) {
    const int o = blockIdx.x, tid = threadIdx.x;
    float s1 = 0.f, s2 = 0.f;
    for (int i = tid; i < 1024; i += 256) {           // 64 n * 16 tt
        const float* p = partials + (size_t)i * 512 + o * 2;
        s1 += p[0]; s2 += p[1];
    }
    __shared__ float r1[256], r2[256];
    r1[tid] = s1; r2[tid] = s2;
    __syncthreads();
    for (int s = 128; s > 0; s >>= 1) {
        if (tid < s) { r1[tid] += r1[tid + s]; r2[tid] += r2[tid + s]; }
        __syncthreads();
    }
    if (tid == 0) {
        const float inv = 1.f / (float)((size_t)BB * NN);
        const float mean = r1[0] * inv;
        const float var  = r2[0] * inv - mean * mean;
        const float sc = gamma[o] * rsqrtf(var + EPSBN);
        scl[o] = sc;
        shf[o] = beta[o] - mean * sc;
    }
}

// ---------------- kernel 5: BN apply + ReLU: y bf16 -> out f32 ----------------
__global__ __launch_bounds__(256) void k_apply(const unsigned short* __restrict__ y,
                                               float* __restrict__ out,
                                               const float* __restrict__ scl,
                                               const float* __restrict__ shf) {
    __shared__ float ssc[CO], ssh[CO];
    const int tid = threadIdx.x;
    ssc[tid] = scl[tid]; ssh[tid] = shf[tid];
    __syncthreads();
    const size_t total8 = (size_t)BB * NN * CO / 8;
    float4* out4 = (float4*)out;
    for (size_t i = (size_t)blockIdx.x * 256 + tid; i < total8; i += (size_t)gridDim.x * 256) {
        const us8 v = *(const us8*)(y + i * 8);
        const int ob = (int)((i * 8) & (CO - 1));
        float4 r0, r1;
        r0.x = fmaxf(0.f, bf2f(v[0]) * ssc[ob + 0] + ssh[ob + 0]);
        r0.y = fmaxf(0.f, bf2f(v[1]) * ssc[ob + 1] + ssh[ob + 1]);
        r0.z = fmaxf(0.f, bf2f(v[2]) * ssc[ob + 2] + ssh[ob + 2]);
        r0.w = fmaxf(0.f, bf2f(v[3]) * ssc[ob + 3] + ssh[ob + 3]);
        r1.x = fmaxf(0.f, bf2f(v[4]) * ssc[ob + 4] + ssh[ob + 4]);
        r1.y = fmaxf(0.f, bf2f(v[5]) * ssc[ob + 5] + ssh[ob + 5]);
        r1.z = fmaxf(0.f, bf2f(v[6]) * ssc[ob + 6] + ssh[ob + 6]);
        r1.w = fmaxf(0.f, bf2f(v[7]) * ssc[ob + 7] + ssh[ob + 7]);
        out4[i * 2]     = r0;
        out4[i * 2 + 1] = r1;
    }
}

extern "C" void kernel_launch(void* const* d_in, const int* in_sizes, int n_in,
                              void* d_out, int out_size, void* d_ws, size_t ws_size,
                              hipStream_t stream) {
    const float* x     = (const float*)d_in[0];
    const float* W     = (const float*)d_in[1];
    const float* bgcn  = (const float*)d_in[2];
    const float* wconv = (const float*)d_in[3];
    const float* bconv = (const float*)d_in[4];
    const float* gamma = (const float*)d_in[5];
    const float* beta  = (const float*)d_in[6];
    const int*   ei    = (const int*)d_in[7];
    float* out = (float*)d_out;

    char* ws = (char*)d_ws;
    size_t off = 0;
    __hip_bfloat16* xgcn = (__hip_bfloat16*)(ws + off); off += (size_t)BB * NN * CO * 2;   // 67 MB, [n][b][c]
    __hip_bfloat16* ybuf = (__hip_bfloat16*)(ws + off); off += (size_t)BB * NN * CO * 2;   // 67 MB, [b][n][o]
    __hip_bfloat16* W2f  = (__hip_bfloat16*)(ws + off); off += (size_t)CO * KWIN * CO * 2; // 384 KB, frag-packed
    __hip_bfloat16* Ahat = (__hip_bfloat16*)(ws + off); off += (size_t)NN * NN * 2;        // 8 KB
    __hip_bfloat16* Wtf  = (__hip_bfloat16*)(ws + off); off += (size_t)CO * CIN * 2;       // 64 KB, frag-packed
    float* partials = (float*)(ws + off); off += (size_t)1024 * 512 * 4;                   // 2 MB
    float* scl = (float*)(ws + off); off += 256 * 4;
    float* shf = (float*)(ws + off); off += 256 * 4;

    k_prep<<<897, 256, 0, stream>>>(ei, W, wconv, Ahat, Wtf, W2f);
    k_gcn<<<BB, 256, 0, stream>>>(x, Ahat, Wtf, bgcn, xgcn);
    k_conv<<<dim3(16, 64), 512, 0, stream>>>(xgcn, W2f, bconv, ybuf, partials);
    k_bnstats<<<256, 256, 0, stream>>>(partials, gamma, beta, scl, shf);
    k_apply<<<2048, 256, 0, stream>>>((const unsigned short*)ybuf, out, scl, shf);
}